// Round 1
// baseline (184.285 us; speedup 1.0000x reference)
//
#include <hip/hip_runtime.h>

// LSTM: B=65536 sequences, T=256 steps, E=H=5, x in {0,1}.
// One thread per sequence; all state + weights in registers.
// Gate order (PyTorch): i, f, g, o.

constexpr int TT = 256;
constexpr int EE = 5;
constexpr int HH = 5;
constexpr int GG = 20;  // 4*H

__device__ __forceinline__ float fsigmoid(float v) {
    // 1 / (1 + 2^(-v*log2(e)))
    float e = __builtin_amdgcn_exp2f(v * -1.4426950408889634f);
    return __builtin_amdgcn_rcpf(1.0f + e);
}

__device__ __forceinline__ float ftanh(float v) {
    // 1 - 2 / (1 + 2^(2*v*log2(e)))
    float e = __builtin_amdgcn_exp2f(v * 2.8853900817779268f);
    return fmaf(-2.0f, __builtin_amdgcn_rcpf(1.0f + e), 1.0f);
}

__global__ __launch_bounds__(256, 1) void lstm_fused(
    const int* __restrict__ x,       // [B, T]
    const float* __restrict__ emb,   // [2, E]
    const float* __restrict__ W_ih,  // [4H, E]
    const float* __restrict__ W_hh,  // [4H, H]
    const float* __restrict__ b_ih,  // [4H]
    const float* __restrict__ b_hh,  // [4H]
    const float* __restrict__ W_lin, // [2, H]
    const float* __restrict__ b_lin, // [2]
    float* __restrict__ out)         // [B, 2]
{
    const int b = blockIdx.x * blockDim.x + threadIdx.x;

    // ---- uniform weight loads (compiler promotes to SGPR/VGPR constants) ----
    float whh[GG][HH];
#pragma unroll
    for (int g = 0; g < GG; ++g)
#pragma unroll
        for (int j = 0; j < HH; ++j)
            whh[g][j] = W_hh[g * HH + j];

    // base[g]  = gate input when x=0 (includes both biases)
    // delta[g] = (gate input when x=1) - base[g]
    float base[GG], delta[GG];
#pragma unroll
    for (int g = 0; g < GG; ++g) {
        float g0 = b_ih[g] + b_hh[g];
        float g1 = g0;
#pragma unroll
        for (int e = 0; e < EE; ++e) {
            float w = W_ih[g * EE + e];
            g0 = fmaf(w, emb[e], g0);        // emb[0][e]
            g1 = fmaf(w, emb[EE + e], g1);   // emb[1][e]
        }
        base[g] = g0;
        delta[g] = g1 - g0;
    }

    float h[HH] = {0.f, 0.f, 0.f, 0.f, 0.f};
    float c[HH] = {0.f, 0.f, 0.f, 0.f, 0.f};

    auto step = [&](int xt) {
        const float xtf = (float)xt;
        float gate[GG];
#pragma unroll
        for (int g = 0; g < GG; ++g) {
            float v = fmaf(xtf, delta[g], base[g]);
#pragma unroll
            for (int j = 0; j < HH; ++j)
                v = fmaf(whh[g][j], h[j], v);
            gate[g] = v;
        }
#pragma unroll
        for (int j = 0; j < HH; ++j) {
            float ig = fsigmoid(gate[j]);
            float fg = fsigmoid(gate[HH + j]);
            float gg = ftanh(gate[2 * HH + j]);
            float og = fsigmoid(gate[3 * HH + j]);
            float cn = fmaf(fg, c[j], ig * gg);
            c[j] = cn;
            h[j] = og * ftanh(cn);
        }
    };

    // ---- main scan: 64 int4 loads, prefetch-next, 4 steps per iter ----
    const int4* xr = reinterpret_cast<const int4*>(x + (size_t)b * TT);
    int4 cur = xr[0];
#pragma unroll 1
    for (int it = 0; it < TT / 4 - 1; ++it) {
        int4 nxt = xr[it + 1];
        step(cur.x);
        step(cur.y);
        step(cur.z);
        step(cur.w);
        cur = nxt;
    }
    step(cur.x);
    step(cur.y);
    step(cur.z);
    step(cur.w);

    // ---- linear head: out[b][k] = sum_j h[j]*W_lin[k][j] + b_lin[k] ----
    float o0 = b_lin[0], o1 = b_lin[1];
#pragma unroll
    for (int j = 0; j < HH; ++j) {
        o0 = fmaf(W_lin[j], h[j], o0);
        o1 = fmaf(W_lin[HH + j], h[j], o1);
    }
    float2* outv = reinterpret_cast<float2*>(out);
    outv[b] = make_float2(o0, o1);
}

extern "C" void kernel_launch(void* const* d_in, const int* in_sizes, int n_in,
                              void* d_out, int out_size, void* d_ws, size_t ws_size,
                              hipStream_t stream) {
    const int* x        = (const int*)d_in[0];
    const float* emb    = (const float*)d_in[1];
    const float* W_ih   = (const float*)d_in[2];
    const float* W_hh   = (const float*)d_in[3];
    const float* b_ih   = (const float*)d_in[4];
    const float* b_hh   = (const float*)d_in[5];
    const float* W_lin  = (const float*)d_in[6];
    const float* b_lin  = (const float*)d_in[7];
    float* out          = (float*)d_out;

    const int B = in_sizes[0] / TT;          // 65536
    const int block = 256;
    const int grid = B / block;               // 256 blocks -> 1024 waves

    lstm_fused<<<grid, block, 0, stream>>>(x, emb, W_ih, W_hh, b_ih, b_hh,
                                           W_lin, b_lin, out);
}

// Round 2
// 107.959 us; speedup vs baseline: 1.7070x; 1.7070x over previous
//
#include <hip/hip_runtime.h>

// LSTM: B=65536 seqs, T=256, E=H=5, x in {0,1}. One thread per sequence.
// All weights pinned in VGPRs (occupancy is structurally 1 wave/SIMD, so
// VGPR budget is free). Gates packed in float2 -> v_pk_fma_f32.
// Activation scale constants folded into the weights:
//   sigmoid(v) = rcp(1 + exp2(v * -log2 e))   -> rows pre-scaled by -log2 e
//   tanh(v)    = 1 - 2*rcp(1 + exp2(v*2log2e))-> g-rows pre-scaled by 2log2 e

typedef float v2f __attribute__((ext_vector_type(2)));

constexpr int TT = 256;
constexpr int EE = 5;
constexpr int HH = 5;
constexpr int GG = 20;  // 4*H
constexpr int GP = 10;  // gate pairs

__device__ __forceinline__ float fexp2(float v) { return __builtin_amdgcn_exp2f(v); }
__device__ __forceinline__ float frcp(float v)  { return __builtin_amdgcn_rcpf(v); }

__global__ __launch_bounds__(256, 1) void lstm_fused(
    const int* __restrict__ x,       // [B, T]
    const float* __restrict__ emb,   // [2, E]
    const float* __restrict__ W_ih,  // [4H, E]
    const float* __restrict__ W_hh,  // [4H, H]
    const float* __restrict__ b_ih,  // [4H]
    const float* __restrict__ b_hh,  // [4H]
    const float* __restrict__ W_lin, // [2, H]
    const float* __restrict__ b_lin, // [2]
    float* __restrict__ out)         // [B, 2]
{
    const int b = blockIdx.x * blockDim.x + threadIdx.x;

    const float NL2E  = -1.4426950408889634f;  // -log2(e)   (sigmoid gates)
    const float T2L2E =  2.8853900817779268f;  // 2*log2(e)  (tanh gate)

    // ---- precompute scaled base/delta per gate (x=0 value, x=1 delta) ----
    float base_s[GG], delta_s[GG];
#pragma unroll
    for (int g = 0; g < GG; ++g) {
        float g0 = b_ih[g] + b_hh[g];
        float g1 = g0;
#pragma unroll
        for (int e = 0; e < EE; ++e) {
            float w = W_ih[g * EE + e];
            g0 = fmaf(w, emb[e], g0);        // emb[0][e]
            g1 = fmaf(w, emb[EE + e], g1);   // emb[1][e]
        }
        float s = (g >= 10 && g < 15) ? T2L2E : NL2E;
        base_s[g]  = s * g0;
        delta_s[g] = s * (g1 - g0);
    }

    // ---- pack into float2 pairs and PIN into VGPRs ----
    // (asm "+v" makes the value non-provably-uniform -> stays in VGPRs; no
    //  in-loop SGPR reload / readlane traffic)
    v2f basepk[GP], deltapk[GP];
    v2f wpk[HH][GP];   // wpk[j][p] = scaled {W_hh[2p][j], W_hh[2p+1][j]}
#pragma unroll
    for (int p = 0; p < GP; ++p) {
        float b0 = base_s[2*p],  b1 = base_s[2*p+1];
        float d0 = delta_s[2*p], d1 = delta_s[2*p+1];
        asm volatile("" : "+v"(b0), "+v"(b1), "+v"(d0), "+v"(d1));
        basepk[p][0] = b0;  basepk[p][1] = b1;
        deltapk[p][0] = d0; deltapk[p][1] = d1;
        float s0 = (2*p   >= 10 && 2*p   < 15) ? T2L2E : NL2E;
        float s1 = (2*p+1 >= 10 && 2*p+1 < 15) ? T2L2E : NL2E;
#pragma unroll
        for (int j = 0; j < HH; ++j) {
            float w0 = s0 * W_hh[(2*p)   * HH + j];
            float w1 = s1 * W_hh[(2*p+1) * HH + j];
            asm volatile("" : "+v"(w0), "+v"(w1));
            wpk[j][p][0] = w0; wpk[j][p][1] = w1;
        }
    }

    float h[HH] = {0.f, 0.f, 0.f, 0.f, 0.f};
    float c[HH] = {0.f, 0.f, 0.f, 0.f, 0.f};

    auto step = [&](int xt) {
        const float xtf = (float)xt;
        v2f xpk; xpk[0] = xtf; xpk[1] = xtf;
        v2f g[GP];
#pragma unroll
        for (int p = 0; p < GP; ++p)
            g[p] = __builtin_elementwise_fma(xpk, deltapk[p], basepk[p]);
#pragma unroll
        for (int j = 0; j < HH; ++j) {
            v2f hj; hj[0] = h[j]; hj[1] = h[j];
#pragma unroll
            for (int p = 0; p < GP; ++p)
                g[p] = __builtin_elementwise_fma(wpk[j][p], hj, g[p]);
        }
#pragma unroll
        for (int j = 0; j < HH; ++j) {
            float gi = g[(j)      >> 1][(j)      & 1];
            float gf = g[(5 + j)  >> 1][(5 + j)  & 1];
            float gg = g[(10 + j) >> 1][(10 + j) & 1];
            float go = g[(15 + j) >> 1][(15 + j) & 1];
            float iv = frcp(1.0f + fexp2(gi));                    // sigmoid
            float fv = frcp(1.0f + fexp2(gf));                    // sigmoid
            float gv = fmaf(-2.0f, frcp(1.0f + fexp2(gg)), 1.0f); // tanh
            float ov = frcp(1.0f + fexp2(go));                    // sigmoid
            float cn = fmaf(fv, c[j], iv * gv);
            c[j] = cn;
            float tc = fmaf(-2.0f, frcp(1.0f + fexp2(cn * T2L2E)), 1.0f);
            h[j] = ov * tc;
        }
    };

    // ---- main scan: 64 int4 loads, prefetch-next, 4 steps per iter ----
    const int4* xr = reinterpret_cast<const int4*>(x + (size_t)b * TT);
    int4 cur = xr[0];
#pragma unroll 1
    for (int it = 0; it < TT / 4 - 1; ++it) {
        int4 nxt = xr[it + 1];
        step(cur.x);
        step(cur.y);
        step(cur.z);
        step(cur.w);
        cur = nxt;
    }
    step(cur.x);
    step(cur.y);
    step(cur.z);
    step(cur.w);

    // ---- linear head ----
    float o0 = b_lin[0], o1 = b_lin[1];
#pragma unroll
    for (int j = 0; j < HH; ++j) {
        o0 = fmaf(W_lin[j],      h[j], o0);
        o1 = fmaf(W_lin[HH + j], h[j], o1);
    }
    reinterpret_cast<float2*>(out)[b] = make_float2(o0, o1);
}

extern "C" void kernel_launch(void* const* d_in, const int* in_sizes, int n_in,
                              void* d_out, int out_size, void* d_ws, size_t ws_size,
                              hipStream_t stream) {
    const int* x        = (const int*)d_in[0];
    const float* emb    = (const float*)d_in[1];
    const float* W_ih   = (const float*)d_in[2];
    const float* W_hh   = (const float*)d_in[3];
    const float* b_ih   = (const float*)d_in[4];
    const float* b_hh   = (const float*)d_in[5];
    const float* W_lin  = (const float*)d_in[6];
    const float* b_lin  = (const float*)d_in[7];
    float* out          = (float*)d_out;

    const int B = in_sizes[0] / TT;   // 65536
    const int block = 256;
    const int grid = B / block;       // 256 blocks -> 1024 waves -> 1/SIMD

    lstm_fused<<<grid, block, 0, stream>>>(x, emb, W_ih, W_hh, b_ih, b_hh,
                                           W_lin, b_lin, out);
}

// Round 3
// 95.582 us; speedup vs baseline: 1.9280x; 1.1295x over previous
//
#include <hip/hip_runtime.h>

// LSTM: B=65536 seqs, T=256, E=H=5, x in {0,1}. One thread per sequence.
// Trans-pipe-bound at 1 wave/SIMD -> minimize v_exp/v_rcp count:
//   sigma(i)*tanh(g) and sigma(f)*c share ONE rcp via common denominator:
//     c' = [chat*Ai*Ag + 2log2e*(Eg-1)*Af] / (Ai*Af*Ag),  A* = 1+E*
//   h  = sigma(o)*tanh(c') = (Ec-1)/((1+Eo)(1+Ec))        -> one rcp
//   plus cross-j rcp pairing: rcp(Da*Db) serves two units.
//   c tracked pre-scaled (chat = 2log2e * c) so Ec = exp2(chat), no extra mul.
// Per step: 25 exp2 + 6 rcp (was 25+25) + ~140 full-rate VALU.

typedef float v2f __attribute__((ext_vector_type(2)));

constexpr int TT = 256;
constexpr int EE = 5;
constexpr int HH = 5;
constexpr int GG = 20;  // 4*H
constexpr int GP = 10;  // gate pairs

__device__ __forceinline__ float fexp2(float v) { return __builtin_amdgcn_exp2f(v); }
__device__ __forceinline__ float frcp(float v)  { return __builtin_amdgcn_rcpf(v); }

__global__ __launch_bounds__(256, 1) void lstm_fused(
    const int* __restrict__ x,       // [B, T]
    const float* __restrict__ emb,   // [2, E]
    const float* __restrict__ W_ih,  // [4H, E]
    const float* __restrict__ W_hh,  // [4H, H]
    const float* __restrict__ b_ih,  // [4H]
    const float* __restrict__ b_hh,  // [4H]
    const float* __restrict__ W_lin, // [2, H]
    const float* __restrict__ b_lin, // [2]
    float* __restrict__ out)         // [B, 2]
{
    const int b = blockIdx.x * blockDim.x + threadIdx.x;

    const float NL2E  = -1.4426950408889634f;  // -log2(e)   (sigmoid gates)
    const float T2L2E =  2.8853900817779268f;  // 2*log2(e)  (tanh gate)

    // ---- precompute scaled base/delta per gate (x=0 value, x=1 delta) ----
    float base_s[GG], delta_s[GG];
#pragma unroll
    for (int g = 0; g < GG; ++g) {
        float g0 = b_ih[g] + b_hh[g];
        float g1 = g0;
#pragma unroll
        for (int e = 0; e < EE; ++e) {
            float w = W_ih[g * EE + e];
            g0 = fmaf(w, emb[e], g0);        // emb[0][e]
            g1 = fmaf(w, emb[EE + e], g1);   // emb[1][e]
        }
        float s = (g >= 10 && g < 15) ? T2L2E : NL2E;
        base_s[g]  = s * g0;
        delta_s[g] = s * (g1 - g0);
    }

    // ---- pack into float2 pairs and PIN into VGPRs (asm "+v" defeats
    //      uniformity analysis -> no in-loop SGPR reload traffic) ----
    v2f basepk[GP], deltapk[GP];
    v2f wpk[HH][GP];   // wpk[j][p] = scaled {W_hh[2p][j], W_hh[2p+1][j]}
#pragma unroll
    for (int p = 0; p < GP; ++p) {
        float b0 = base_s[2*p],  b1 = base_s[2*p+1];
        float d0 = delta_s[2*p], d1 = delta_s[2*p+1];
        asm volatile("" : "+v"(b0), "+v"(b1), "+v"(d0), "+v"(d1));
        basepk[p][0] = b0;  basepk[p][1] = b1;
        deltapk[p][0] = d0; deltapk[p][1] = d1;
        float s0 = (2*p   >= 10 && 2*p   < 15) ? T2L2E : NL2E;
        float s1 = (2*p+1 >= 10 && 2*p+1 < 15) ? T2L2E : NL2E;
#pragma unroll
        for (int j = 0; j < HH; ++j) {
            float w0 = s0 * W_hh[(2*p)   * HH + j];
            float w1 = s1 * W_hh[(2*p+1) * HH + j];
            asm volatile("" : "+v"(w0), "+v"(w1));
            wpk[j][p][0] = w0; wpk[j][p][1] = w1;
        }
    }

    float h[HH]    = {0.f, 0.f, 0.f, 0.f, 0.f};
    float chat[HH] = {0.f, 0.f, 0.f, 0.f, 0.f};  // 2*log2(e) * c

    auto step = [&](int xt) {
        const float xtf = (float)xt;
        v2f xpk; xpk[0] = xtf; xpk[1] = xtf;
        v2f g[GP];
#pragma unroll
        for (int p = 0; p < GP; ++p)
            g[p] = __builtin_elementwise_fma(xpk, deltapk[p], basepk[p]);
#pragma unroll
        for (int j = 0; j < HH; ++j) {
            v2f hj; hj[0] = h[j]; hj[1] = h[j];
#pragma unroll
            for (int p = 0; p < GP; ++p)
                g[p] = __builtin_elementwise_fma(wpk[j][p], hj, g[p]);
        }
        auto G = [&](int idx) -> float { return g[idx >> 1][idx & 1]; };

        // ---- c-phase: N_j / D_j with one shared denominator per unit ----
        float N[HH], D[HH];
#pragma unroll
        for (int j = 0; j < HH; ++j) {
            float Ei = fexp2(G(j));          // e^{-i}
            float Ef = fexp2(G(5 + j));      // e^{-f}
            float Eg = fexp2(G(10 + j));     // e^{2g}
            float Ai = 1.0f + Ei, Af = 1.0f + Ef, Ag = 1.0f + Eg;
            float P  = Ai * Ag;
            D[j] = P * Af;
            float t = fmaf(T2L2E, Eg, -T2L2E);        // 2log2e*(Eg-1)
            N[j] = fmaf(chat[j], P, t * Af);
        }
        {   // paired reciprocals: (0,1), (2,3), 4
            float R01 = frcp(D[0] * D[1]);
            chat[0] = (N[0] * D[1]) * R01;
            chat[1] = (N[1] * D[0]) * R01;
            float R23 = frcp(D[2] * D[3]);
            chat[2] = (N[2] * D[3]) * R23;
            chat[3] = (N[3] * D[2]) * R23;
            chat[4] = N[4] * frcp(D[4]);
        }

        // ---- h-phase: h = (Ec-1)/((1+Eo)(1+Ec)) ----
        float T2[HH], D2[HH];
#pragma unroll
        for (int j = 0; j < HH; ++j) {
            float Eo = fexp2(G(15 + j));     // e^{-o}
            float Ec = fexp2(chat[j]);       // e^{2c}
            D2[j] = (1.0f + Eo) * (1.0f + Ec);
            T2[j] = Ec - 1.0f;
        }
        {
            float R01 = frcp(D2[0] * D2[1]);
            h[0] = (T2[0] * D2[1]) * R01;
            h[1] = (T2[1] * D2[0]) * R01;
            float R23 = frcp(D2[2] * D2[3]);
            h[2] = (T2[2] * D2[3]) * R23;
            h[3] = (T2[3] * D2[2]) * R23;
            h[4] = T2[4] * frcp(D2[4]);
        }
    };

    // ---- main scan: 64 int4 loads, prefetch-next, 4 steps per iter ----
    const int4* xr = reinterpret_cast<const int4*>(x + (size_t)b * TT);
    int4 cur = xr[0];
#pragma unroll 1
    for (int it = 0; it < TT / 4 - 1; ++it) {
        int4 nxt = xr[it + 1];
        step(cur.x);
        step(cur.y);
        step(cur.z);
        step(cur.w);
        cur = nxt;
    }
    step(cur.x);
    step(cur.y);
    step(cur.z);
    step(cur.w);

    // ---- linear head ----
    float o0 = b_lin[0], o1 = b_lin[1];
#pragma unroll
    for (int j = 0; j < HH; ++j) {
        o0 = fmaf(W_lin[j],      h[j], o0);
        o1 = fmaf(W_lin[HH + j], h[j], o1);
    }
    reinterpret_cast<float2*>(out)[b] = make_float2(o0, o1);
}

extern "C" void kernel_launch(void* const* d_in, const int* in_sizes, int n_in,
                              void* d_out, int out_size, void* d_ws, size_t ws_size,
                              hipStream_t stream) {
    const int* x        = (const int*)d_in[0];
    const float* emb    = (const float*)d_in[1];
    const float* W_ih   = (const float*)d_in[2];
    const float* W_hh   = (const float*)d_in[3];
    const float* b_ih   = (const float*)d_in[4];
    const float* b_hh   = (const float*)d_in[5];
    const float* W_lin  = (const float*)d_in[6];
    const float* b_lin  = (const float*)d_in[7];
    float* out          = (float*)d_out;

    const int B = in_sizes[0] / TT;   // 65536
    const int block = 256;
    const int grid = B / block;       // 256 blocks -> 1024 waves -> 1/SIMD

    lstm_fused<<<grid, block, 0, stream>>>(x, emb, W_ih, W_hh, b_ih, b_hh,
                                           W_lin, b_lin, out);
}